// Round 15
// baseline (477.710 us; speedup 1.0000x reference)
//
#include <hip/hip_runtime.h>
#include <hip/hip_bf16.h>

#define N_NODES 50000
#define N_EDGES 800000
#define C_IN    128
#define C_H     64
#define C_HU    32                         // u32 words per bf16 row
#define N_LAYER 9
#define N_GRAPH 10
#define N_PER_G 5000
#define NSB     ((N_NODES + 255) / 256)    // 196 scan blocks
#define NPB     16                         // nodes per block in layer kernel
#define NPX     (N_NODES / 8)              // 6250 nodes per XCD partition

typedef unsigned int  u32;
typedef unsigned short u16;
typedef __bf16 bf16x8 __attribute__((ext_vector_type(8)));
typedef float  f32x4  __attribute__((ext_vector_type(4)));

__device__ __forceinline__ float bflo(u32 u) { return __uint_as_float(u << 16); }
__device__ __forceinline__ float bfhi(u32 u) { return __uint_as_float(u & 0xffff0000u); }
__device__ __forceinline__ u16 f2bf(float f) {            // RNE f32 -> bf16
    u32 u = __float_as_uint(f);
    u32 r = u + 0x7fffu + ((u >> 16) & 1u);
    return (u16)(r >> 16);
}
__device__ __forceinline__ void add8(float* acc, uint4 v) {
    acc[0] += bflo(v.x); acc[1] += bfhi(v.x);
    acc[2] += bflo(v.y); acc[3] += bfhi(v.y);
    acc[4] += bflo(v.z); acc[5] += bfhi(v.z);
    acc[6] += bflo(v.w); acc[7] += bfhi(v.w);
}

// ---------------- CSR build (XCD-partitioned by dst range, int4 edge reads) ----------------

__global__ __launch_bounds__(256) void count_kernel(const int4* __restrict__ dst4,
                                                    int* __restrict__ cnt) {
    int grp = blockIdx.x & 7;
    int blk = blockIdx.x >> 3;          // 0..127
    int lo = grp * NPX, hi = lo + NPX;
    for (int q = blk * 256 + threadIdx.x; q < N_EDGES / 4; q += 128 * 256) {
        int4 d = dst4[q];
        if (d.x >= lo && d.x < hi) atomicAdd(&cnt[d.x], 1);
        if (d.y >= lo && d.y < hi) atomicAdd(&cnt[d.y], 1);
        if (d.z >= lo && d.z < hi) atomicAdd(&cnt[d.z], 1);
        if (d.w >= lo && d.w < hi) atomicAdd(&cnt[d.w], 1);
    }
}

__global__ __launch_bounds__(256) void bsum_kernel(const int* __restrict__ cnt,
                                                   int* __restrict__ bsum) {
    int i = blockIdx.x * 256 + threadIdx.x;
    int v = (i < N_NODES) ? cnt[i] : 0;
#pragma unroll
    for (int off = 32; off; off >>= 1) v += __shfl_down(v, off);
    __shared__ int s[4];
    if ((threadIdx.x & 63) == 0) s[threadIdx.x >> 6] = v;
    __syncthreads();
    if (threadIdx.x == 0) bsum[blockIdx.x] = s[0] + s[1] + s[2] + s[3];
}

__global__ __launch_bounds__(256) void scan2_kernel(const int* __restrict__ cnt,
                                                    const int* __restrict__ bsum,
                                                    int* __restrict__ rowStart,
                                                    int* __restrict__ cursor,
                                                    float* __restrict__ dinv) {
    int b = blockIdx.x, t = threadIdx.x;
    int v = (t < b) ? bsum[t] : 0;
#pragma unroll
    for (int off = 32; off; off >>= 1) v += __shfl_down(v, off);
    __shared__ int sw[4];
    __shared__ int soff;
    if ((t & 63) == 0) sw[t >> 6] = v;
    __syncthreads();
    if (t == 0) soff = sw[0] + sw[1] + sw[2] + sw[3];

    int i = b * 256 + t;
    int c = (i < N_NODES) ? cnt[i] : 0;
    __shared__ int sd[256];
    sd[t] = c;
    __syncthreads();
#pragma unroll
    for (int off = 1; off < 256; off <<= 1) {
        int x = sd[t];
        int y = (t >= off) ? sd[t - off] : 0;
        __syncthreads();
        sd[t] = x + y;
        __syncthreads();
    }
    if (i < N_NODES) {
        int rs = soff + sd[t] - c;
        rowStart[i] = rs;
        cursor[i] = rs;
        dinv[i] = rsqrtf((float)c + 1.0f);
    }
}

__global__ __launch_bounds__(256) void scatter_kernel(const int4* __restrict__ src4,
                                                      const int4* __restrict__ dst4,
                                                      int* __restrict__ cursor,
                                                      u16* __restrict__ csr16) {
    int grp = blockIdx.x & 7;
    int blk = blockIdx.x >> 3;          // 0..127
    int lo = grp * NPX, hi = lo + NPX;
    for (int q = blk * 256 + threadIdx.x; q < N_EDGES / 4; q += 128 * 256) {
        int4 d = dst4[q];
        int4 s = src4[q];
        if (d.x >= lo && d.x < hi) { int p = atomicAdd(&cursor[d.x], 1); csr16[p] = (u16)s.x; }
        if (d.y >= lo && d.y < hi) { int p = atomicAdd(&cursor[d.y], 1); csr16[p] = (u16)s.y; }
        if (d.z >= lo && d.z < hi) { int p = atomicAdd(&cursor[d.z], 1); csr16[p] = (u16)s.z; }
        if (d.w >= lo && d.w < hi) { int p = atomicAdd(&cursor[d.w], 1); csr16[p] = (u16)s.w; }
    }
}

// ---------------- weight pre-transpose into MFMA frag order ----------------
// Wt[layer][(((ct*2+ks)*4+lg)*16+lr)*8+j] = W_layer[(ks*32+lg*8+j)*64 + ct*16+lr]
// -> per-lane B-frag load becomes one b128 per k-step.

__global__ __launch_bounds__(256) void wtrans_kernel(const float* __restrict__ Ws,
                                                     const float* __restrict__ Wn,
                                                     u16* __restrict__ Wt) {
    int i = blockIdx.x * 256 + threadIdx.x;           // 9*4096 total
    if (i >= 9 * 4096) return;
    int layer = i >> 12, t = i & 4095;
    int k = t >> 6, c = t & 63;
    const float* W = (layer < 8) ? (Ws + layer * 4096) : Wn;
    int ct = c >> 4, lr = c & 15, ks = k >> 5, lg = (k >> 3) & 3, j = k & 7;
    Wt[layer * 4096 + (((ct * 2 + ks) * 4 + lg) * 16 + lr) * 8 + j] = f2bf(W[k * 64 + c]);
}

// ---------------- layer 0 input GEMM via MFMA: h'0 = (x @ W0) * dinv, bf16 out ----------------

__global__ __launch_bounds__(256) void gemm0_kernel(const float* __restrict__ x,
                                                    const float* __restrict__ W0,
                                                    const float* __restrict__ dinv,
                                                    u16* __restrict__ out) {
    __shared__ float Wlds[C_IN * C_H];   // 32 KB fp32
    for (int t = threadIdx.x; t < (C_IN * C_H) / 4; t += 256)
        *(float4*)&Wlds[t * 4] = *(const float4*)&W0[t * 4];
    __syncthreads();

    int wid = threadIdx.x >> 6, lane = threadIdx.x & 63;
    int lr = lane & 15, lg = lane >> 4;

    bf16x8 bfr[4][4];   // [col-tile][k-step]
#pragma unroll
    for (int ct = 0; ct < 4; ct++)
#pragma unroll
        for (int kk = 0; kk < 4; kk++)
#pragma unroll
            for (int j = 0; j < 8; j++)
                bfr[ct][kk][j] = (__bf16)Wlds[(kk * 32 + lg * 8 + j) * C_H + ct * 16 + lr];

    for (int t = blockIdx.x * 4 + wid; t < N_NODES / 16; t += gridDim.x * 4) {
        int row0 = t * 16;
        bf16x8 af[4];
#pragma unroll
        for (int kk = 0; kk < 4; kk++) {
            const float* xp = x + (size_t)(row0 + lr) * C_IN + kk * 32 + lg * 8;
            float4 p0 = *(const float4*)xp;
            float4 p1 = *(const float4*)(xp + 4);
            af[kk][0] = (__bf16)p0.x; af[kk][1] = (__bf16)p0.y;
            af[kk][2] = (__bf16)p0.z; af[kk][3] = (__bf16)p0.w;
            af[kk][4] = (__bf16)p1.x; af[kk][5] = (__bf16)p1.y;
            af[kk][6] = (__bf16)p1.z; af[kk][7] = (__bf16)p1.w;
        }
        f32x4 acc[4];
#pragma unroll
        for (int ct = 0; ct < 4; ct++) acc[ct] = (f32x4){0.f, 0.f, 0.f, 0.f};
#pragma unroll
        for (int ct = 0; ct < 4; ct++)
#pragma unroll
            for (int kk = 0; kk < 4; kk++)
                acc[ct] = __builtin_amdgcn_mfma_f32_16x16x32_bf16(af[kk], bfr[ct][kk], acc[ct], 0, 0, 0);
#pragma unroll
        for (int reg = 0; reg < 4; reg++) {
            int rr = row0 + lg * 4 + reg;
            float dv = dinv[rr];
#pragma unroll
            for (int ct = 0; ct < 4; ct++)
                out[(size_t)rr * C_H + ct * 16 + lr] = f2bf(acc[ct][reg] * dv);
        }
    }
}

// ---------------- fused layer: depth-2 pipelined gather + MFMA GEMV (frag-packed W) --------

#define CLOAD(dst, n, d, b_)                                                      \
    {                                                                             \
        int e_ = (b_) + 8 * (d) + g;                                              \
        int s_ = csr16[sq##n + ((e_ < dq##n) ? e_ : 0)];                          \
        dst = (e_ < dq##n) ? s_ : N_NODES;                                        \
    }

#define ROWAS(v_, s_) v_ = *(const uint4*)(hw + (size_t)(s_) * C_HU + r * 4);

#define RED(Aq)                                                                   \
    _Pragma("unroll")                                                             \
    for (int c = 0; c < 8; c++) {                                                 \
        Aq[c] += __shfl_xor(Aq[c], 8);                                            \
        Aq[c] += __shfl_xor(Aq[c], 16);                                           \
        Aq[c] += __shfl_xor(Aq[c], 32);                                           \
    }

#define EPILOG(q, iq, Aq, svq)                                                    \
    {                                                                             \
        float di = dinv[iq];                                                      \
        if (g == 0) {                                                             \
            float h0 = fmaxf(di * (Aq[0] + bflo(svq.x)) + b8[0], 0.f);            \
            float h1 = fmaxf(di * (Aq[1] + bfhi(svq.x)) + b8[1], 0.f);            \
            float h2 = fmaxf(di * (Aq[2] + bflo(svq.y)) + b8[2], 0.f);            \
            float h3 = fmaxf(di * (Aq[3] + bfhi(svq.y)) + b8[3], 0.f);            \
            float h4 = fmaxf(di * (Aq[4] + bflo(svq.z)) + b8[4], 0.f);            \
            float h5 = fmaxf(di * (Aq[5] + bfhi(svq.z)) + b8[5], 0.f);            \
            float h6 = fmaxf(di * (Aq[6] + bflo(svq.w)) + b8[6], 0.f);            \
            float h7 = fmaxf(di * (Aq[7] + bfhi(svq.w)) + b8[7], 0.f);            \
            uint4 pk;                                                             \
            pk.x = (u32)f2bf(h0) | ((u32)f2bf(h1) << 16);                         \
            pk.y = (u32)f2bf(h2) | ((u32)f2bf(h3) << 16);                         \
            pk.z = (u32)f2bf(h4) | ((u32)f2bf(h5) << 16);                         \
            pk.w = (u32)f2bf(h6) | ((u32)f2bf(h7) << 16);                         \
            int n_ = wave * 4 + q;                                                \
            int rs_ = r ^ (n_ & 7);     /* chunk swizzle: 16B chunks */           \
            *(uint4*)&hbuf32[n_ * 32 + rs_ * 4] = pk;                             \
        }                                                                         \
    }

__global__ __launch_bounds__(256) void layer_kernel(const u32* __restrict__ hw,
                                                    const int* __restrict__ rowStart,
                                                    const int* __restrict__ cnt,
                                                    const u16* __restrict__ csr16,
                                                    const float* __restrict__ dinv,
                                                    const float* __restrict__ bias,
                                                    const u16* __restrict__ wtL,
                                                    int scaled,
                                                    u16* __restrict__ out) {
    __shared__ u32 hbuf32[NPB * C_HU];   // 16 nodes x 64ch bf16 = 2 KB

    int wave = threadIdx.x >> 6, lane = threadIdx.x & 63;
    int g = lane >> 3;          // edge sub-group 0..7
    int r = lane & 7;           // channel chunk: channels 8r..8r+7
    int jblock = blockIdx.x * NPB;
    int jbase = jblock + wave * 4;

    int i0 = jbase + 0, i1 = jbase + 1, i2 = jbase + 2, i3 = jbase + 3;
    int sq0 = rowStart[i0], sq1 = rowStart[i1], sq2 = rowStart[i2], sq3 = rowStart[i3];
    int dq0 = cnt[i0], dq1 = cnt[i1], dq2 = cnt[i2], dq3 = cnt[i3];
    int dmax = max(max(dq0, dq1), max(dq2, dq3));

    // prefetch self rows early (consumed in EPILOG)
    uint4 sv0, sv1, sv2, sv3;
    ROWAS(sv0, i0) ROWAS(sv1, i1) ROWAS(sv2, i2) ROWAS(sv3, i3)

    float A0[8] = {0.f,0.f,0.f,0.f,0.f,0.f,0.f,0.f};
    float A1[8] = {0.f,0.f,0.f,0.f,0.f,0.f,0.f,0.f};
    float A2[8] = {0.f,0.f,0.f,0.f,0.f,0.f,0.f,0.f};
    float A3[8] = {0.f,0.f,0.f,0.f,0.f,0.f,0.f,0.f};

    // ---- pipeline prologue: csr batch 0, rows batch 0, csr batch 1 ----
    int s00, s01, s10, s11, s20, s21, s30, s31;
    CLOAD(s00, 0, 0, 0) CLOAD(s01, 0, 1, 0)
    CLOAD(s10, 1, 0, 0) CLOAD(s11, 1, 1, 0)
    CLOAD(s20, 2, 0, 0) CLOAD(s21, 2, 1, 0)
    CLOAD(s30, 3, 0, 0) CLOAD(s31, 3, 1, 0)

    uint4 v00, v01, v10, v11, v20, v21, v30, v31;
    ROWAS(v00, s00) ROWAS(v01, s01)
    ROWAS(v10, s10) ROWAS(v11, s11)
    ROWAS(v20, s20) ROWAS(v21, s21)
    ROWAS(v30, s30) ROWAS(v31, s31)

    int t00, t01, t10, t11, t20, t21, t30, t31;
    CLOAD(t00, 0, 0, 16) CLOAD(t01, 0, 1, 16)
    CLOAD(t10, 1, 0, 16) CLOAD(t11, 1, 1, 16)
    CLOAD(t20, 2, 0, 16) CLOAD(t21, 2, 1, 16)
    CLOAD(t30, 3, 0, 16) CLOAD(t31, 3, 1, 16)

    for (int base = 0; base < dmax; base += 16) {
        uint4 n00, n01, n10, n11, n20, n21, n30, n31;
        ROWAS(n00, t00) ROWAS(n01, t01)
        ROWAS(n10, t10) ROWAS(n11, t11)
        ROWAS(n20, t20) ROWAS(n21, t21)
        ROWAS(n30, t30) ROWAS(n31, t31)
        int nb = base + 32;
        int u00, u01, u10, u11, u20, u21, u30, u31;
        CLOAD(u00, 0, 0, nb) CLOAD(u01, 0, 1, nb)
        CLOAD(u10, 1, 0, nb) CLOAD(u11, 1, 1, nb)
        CLOAD(u20, 2, 0, nb) CLOAD(u21, 2, 1, nb)
        CLOAD(u30, 3, 0, nb) CLOAD(u31, 3, 1, nb)
        add8(A0, v00); add8(A0, v01);
        add8(A1, v10); add8(A1, v11);
        add8(A2, v20); add8(A2, v21);
        add8(A3, v30); add8(A3, v31);
        v00 = n00; v01 = n01; v10 = n10; v11 = n11;
        v20 = n20; v21 = n21; v30 = n30; v31 = n31;
        t00 = u00; t01 = u01; t10 = u10; t11 = u11;
        t20 = u20; t21 = u21; t30 = u30; t31 = u31;
    }

    RED(A0) RED(A1) RED(A2) RED(A3)

    float b8[8];
    *(float4*)&b8[0] = *(const float4*)(bias + r * 8);
    *(float4*)&b8[4] = *(const float4*)(bias + r * 8 + 4);

    EPILOG(0, i0, A0, sv0)
    EPILOG(1, i1, A1, sv1)
    EPILOG(2, i2, A2, sv2)
    EPILOG(3, i3, A3, sv3)

    __syncthreads();   // hbuf visibility

    // ---- GEMV via MFMA: wave ct computes cols ct*16..+15 for all 16 nodes ----
    {
        int ct = wave;
        int lr = lane & 15, lg = lane >> 4;
        bf16x8 bw0 = *(const bf16x8*)&wtL[(((ct * 2 + 0) * 4 + lg) * 16 + lr) * 8];
        bf16x8 bw1 = *(const bf16x8*)&wtL[(((ct * 2 + 1) * 4 + lg) * 16 + lr) * 8];
        const u16* hb = (const u16*)hbuf32;
        bf16x8 ah[2];
#pragma unroll
        for (int ks = 0; ks < 2; ks++) {
            int c = lg + 4 * ks;
            int cs = c ^ (lr & 7);
            ah[ks] = *(const bf16x8*)&hb[lr * C_H + cs * 8];
        }
        f32x4 accv = (f32x4){0.f, 0.f, 0.f, 0.f};
        accv = __builtin_amdgcn_mfma_f32_16x16x32_bf16(ah[0], bw0, accv, 0, 0, 0);
        accv = __builtin_amdgcn_mfma_f32_16x16x32_bf16(ah[1], bw1, accv, 0, 0, 0);
        float4 dv4 = *(const float4*)(dinv + jblock + lg * 4);
        float dvs[4] = {dv4.x, dv4.y, dv4.z, dv4.w};
#pragma unroll
        for (int reg = 0; reg < 4; reg++) {
            int nn = jblock + lg * 4 + reg;
            float sc_ = scaled ? dvs[reg] : 1.0f;
            out[(size_t)nn * C_H + ct * 16 + lr] = f2bf(accv[reg] * sc_);
        }
    }
}

// ---------------- pooling head ----------------

__global__ __launch_bounds__(256) void pool_kernel(const u16* __restrict__ hn,
                                                   float* __restrict__ poolbuf) {
    int g = blockIdx.x >> 4;
    int s = blockIdx.x & 15;
    int lane = threadIdx.x & 63;
    int rg = threadIdx.x >> 6;
    int stream = s * 4 + rg;
    float acc = 0.f;
    for (int r = stream; r < N_PER_G; r += 64)
        acc += bflo((u32)hn[(size_t)(g * N_PER_G + r) * C_H + lane]);
    __shared__ float red[4][C_H];
    red[rg][lane] = acc;
    __syncthreads();
    if (rg == 0) {
        float t = red[0][lane] + red[1][lane] + red[2][lane] + red[3][lane];
        atomicAdd(&poolbuf[g * C_H + lane], t);
    }
}

__global__ void poolwp_kernel(const float* __restrict__ poolbuf,
                              const float* __restrict__ Wp,
                              float* __restrict__ poolwp) {
    int g = blockIdx.x, c = threadIdx.x;
    float o = 0.f;
#pragma unroll 8
    for (int k = 0; k < C_H; k++) o += poolbuf[g * C_H + k] * Wp[k * C_H + c];
    poolwp[g * C_H + c] = o;
}

__global__ __launch_bounds__(256) void final_kernel(const u16* __restrict__ hn,
                                                    const float* __restrict__ poolwp,
                                                    const float* __restrict__ Wa,
                                                    float* __restrict__ out, int n) {
    int wave = threadIdx.x >> 6, lane = threadIdx.x & 63;
    int i = blockIdx.x * 4 + wave;
    if (i >= n) return;
    int g = i / N_PER_G;
    float v = fmaxf(bflo((u32)hn[(size_t)i * C_H + lane]), 0.f) * Wa[lane]
            + fmaxf(poolwp[g * C_H + lane], 0.f) * Wa[C_H + lane];
#pragma unroll
    for (int off = 32; off; off >>= 1) v += __shfl_down(v, off);
    if (lane == 0) out[i] = tanhf(v);
}

// ---------------- launch ----------------

extern "C" void kernel_launch(void* const* d_in, const int* in_sizes, int n_in,
                              void* d_out, int out_size, void* d_ws, size_t ws_size,
                              hipStream_t stream) {
    const float* x   = (const float*)d_in[0];
    const int*   ei  = (const int*)d_in[1];
    const float* W0  = (const float*)d_in[2];
    const float* b0  = (const float*)d_in[3];
    const float* Ws  = (const float*)d_in[4];
    const float* bs  = (const float*)d_in[5];
    const float* Wn  = (const float*)d_in[6];
    const float* Wp  = (const float*)d_in[7];
    const float* Wa  = (const float*)d_in[8];
    float* out = (float*)d_out;

    const int* e_src = ei;
    const int* e_dst = ei + N_EDGES;

    size_t off = 0;
    auto alloc = [&](size_t bytes) { size_t o = off; off = (off + bytes + 255) & ~(size_t)255; return o; };
    char* ws = (char*)d_ws;
    int*   cnt      = (int*)  (ws + alloc(N_NODES * 4));
    int*   rowStart = (int*)  (ws + alloc(N_NODES * 4));
    int*   cursor   = (int*)  (ws + alloc(N_NODES * 4));
    float* dinv     = (float*)(ws + alloc(N_NODES * 4));
    int*   bsum     = (int*)  (ws + alloc(NSB * 4));
    u16*   csr16    = (u16*)  (ws + alloc((size_t)(N_EDGES + 64) * 2));   // +pad
    u16*   Wt       = (u16*)  (ws + alloc((size_t)9 * 4096 * 2));         // frag-packed weights
    u16*   bufA     = (u16*)  (ws + alloc((size_t)(N_NODES + 1) * C_H * 2));  // +1 zero sentinel row
    u16*   bufB     = (u16*)  (ws + alloc((size_t)(N_NODES + 1) * C_H * 2));
    float* poolbuf  = (float*)(ws + alloc(N_GRAPH * C_H * 4));
    float* poolwp   = (float*)(ws + alloc(N_GRAPH * C_H * 4));

    hipMemsetAsync(cnt, 0, N_NODES * 4, stream);
    hipMemsetAsync(poolbuf, 0, N_GRAPH * C_H * 4, stream);
    hipMemsetAsync(bufA + (size_t)N_NODES * C_H, 0, C_H * 2, stream);   // zero sentinel rows
    hipMemsetAsync(bufB + (size_t)N_NODES * C_H, 0, C_H * 2, stream);

    count_kernel<<<1024, 256, 0, stream>>>((const int4*)e_dst, cnt);
    bsum_kernel<<<NSB, 256, 0, stream>>>(cnt, bsum);
    scan2_kernel<<<NSB, 256, 0, stream>>>(cnt, bsum, rowStart, cursor, dinv);
    scatter_kernel<<<1024, 256, 0, stream>>>((const int4*)e_src, (const int4*)e_dst,
                                             cursor, csr16);
    wtrans_kernel<<<144, 256, 0, stream>>>(Ws, Wn, Wt);

    gemm0_kernel<<<391, 256, 0, stream>>>(x, W0, dinv, bufA);   // h'0 = (x@W0)*dinv

    const int LB = N_NODES / NPB;   // 3125
    for (int k = 0; k < N_LAYER; k++) {
        const u16* hin  = (k & 1) ? bufB : bufA;
        u16*       hout = (k & 1) ? bufA : bufB;
        const float* bias = (k == 0) ? b0 : (bs + (k - 1) * C_H);
        const u16* wtL = Wt + k * 4096;
        int scaled = (k < N_LAYER - 1) ? 1 : 0;
        layer_kernel<<<LB, 256, 0, stream>>>((const u32*)hin, rowStart, cnt, csr16,
                                             dinv, bias, wtL, scaled, hout);
    }
    const u16* hn = bufB;   // layer 8 output

    pool_kernel<<<N_GRAPH * 16, 256, 0, stream>>>(hn, poolbuf);
    poolwp_kernel<<<N_GRAPH, C_H, 0, stream>>>(poolbuf, Wp, poolwp);
    final_kernel<<<N_NODES / 4, 256, 0, stream>>>(hn, poolwp, Wa, out, N_NODES);
}

// Round 16
// 430.596 us; speedup vs baseline: 1.1094x; 1.1094x over previous
//
#include <hip/hip_runtime.h>
#include <hip/hip_bf16.h>

#define N_NODES 50000
#define N_EDGES 800000
#define C_IN    128
#define C_H     64
#define C_HU    32                         // u32 words per bf16 row
#define N_LAYER 9
#define N_GRAPH 10
#define N_PER_G 5000
#define NSB     ((N_NODES + 255) / 256)    // 196 scan blocks
#define NPB     16                         // nodes per block in layer kernel
#define NPX     (N_NODES / 8)              // 6250 nodes per XCD partition

typedef unsigned int  u32;
typedef unsigned short u16;
typedef __bf16 bf16x8 __attribute__((ext_vector_type(8)));
typedef float  f32x4  __attribute__((ext_vector_type(4)));

__device__ __forceinline__ float bflo(u32 u) { return __uint_as_float(u << 16); }
__device__ __forceinline__ float bfhi(u32 u) { return __uint_as_float(u & 0xffff0000u); }
__device__ __forceinline__ u16 f2bf(float f) {            // RNE f32 -> bf16
    u32 u = __float_as_uint(f);
    u32 r = u + 0x7fffu + ((u >> 16) & 1u);
    return (u16)(r >> 16);
}
__device__ __forceinline__ void add8(float* acc, uint4 v) {
    acc[0] += bflo(v.x); acc[1] += bfhi(v.x);
    acc[2] += bflo(v.y); acc[3] += bfhi(v.y);
    acc[4] += bflo(v.z); acc[5] += bfhi(v.z);
    acc[6] += bflo(v.w); acc[7] += bfhi(v.w);
}

// ---------------- CSR build (XCD-partitioned by dst range) ----------------

__global__ __launch_bounds__(256) void count_kernel(const int* __restrict__ dst,
                                                    int* __restrict__ cnt) {
    int grp = blockIdx.x & 7;
    int blk = blockIdx.x >> 3;          // 0..127
    int lo = grp * NPX, hi = lo + NPX;
    for (int i = blk * 256 + threadIdx.x; i < N_EDGES; i += 128 * 256) {
        int d = dst[i];
        if (d >= lo && d < hi) atomicAdd(&cnt[d], 1);
    }
}

__global__ __launch_bounds__(256) void bsum_kernel(const int* __restrict__ cnt,
                                                   int* __restrict__ bsum) {
    int i = blockIdx.x * 256 + threadIdx.x;
    int v = (i < N_NODES) ? cnt[i] : 0;
#pragma unroll
    for (int off = 32; off; off >>= 1) v += __shfl_down(v, off);
    __shared__ int s[4];
    if ((threadIdx.x & 63) == 0) s[threadIdx.x >> 6] = v;
    __syncthreads();
    if (threadIdx.x == 0) bsum[blockIdx.x] = s[0] + s[1] + s[2] + s[3];
}

__global__ __launch_bounds__(256) void scan2_kernel(const int* __restrict__ cnt,
                                                    const int* __restrict__ bsum,
                                                    int* __restrict__ rowStart,
                                                    int* __restrict__ cursor,
                                                    float* __restrict__ dinv) {
    int b = blockIdx.x, t = threadIdx.x;
    int v = (t < b) ? bsum[t] : 0;
#pragma unroll
    for (int off = 32; off; off >>= 1) v += __shfl_down(v, off);
    __shared__ int sw[4];
    __shared__ int soff;
    if ((t & 63) == 0) sw[t >> 6] = v;
    __syncthreads();
    if (t == 0) soff = sw[0] + sw[1] + sw[2] + sw[3];

    int i = b * 256 + t;
    int c = (i < N_NODES) ? cnt[i] : 0;
    __shared__ int sd[256];
    sd[t] = c;
    __syncthreads();
#pragma unroll
    for (int off = 1; off < 256; off <<= 1) {
        int x = sd[t];
        int y = (t >= off) ? sd[t - off] : 0;
        __syncthreads();
        sd[t] = x + y;
        __syncthreads();
    }
    if (i < N_NODES) {
        int rs = soff + sd[t] - c;
        rowStart[i] = rs;
        cursor[i] = rs;
        dinv[i] = rsqrtf((float)c + 1.0f);
    }
}

__global__ __launch_bounds__(256) void scatter_kernel(const int* __restrict__ src,
                                                      const int* __restrict__ dst,
                                                      int* __restrict__ cursor,
                                                      u16* __restrict__ csr16) {
    int grp = blockIdx.x & 7;
    int blk = blockIdx.x >> 3;          // 0..127
    int lo = grp * NPX, hi = lo + NPX;
    for (int i = blk * 256 + threadIdx.x; i < N_EDGES; i += 128 * 256) {
        int d = dst[i];
        if (d >= lo && d < hi) {
            int p = atomicAdd(&cursor[d], 1);
            csr16[p] = (u16)src[i];
        }
    }
}

// ---------------- weight pre-transpose into MFMA frag order ----------------
// Wt[layer][(((ct*2+ks)*4+lg)*16+lr)*8+j] = W_layer[(ks*32+lg*8+j)*64 + ct*16+lr]
// -> per-lane B-frag load becomes one coalesced b128 per k-step.

__global__ __launch_bounds__(256) void wtrans_kernel(const float* __restrict__ Ws,
                                                     const float* __restrict__ Wn,
                                                     u16* __restrict__ Wt) {
    int i = blockIdx.x * 256 + threadIdx.x;           // 9*4096 total
    if (i >= 9 * 4096) return;
    int layer = i >> 12, t = i & 4095;
    int k = t >> 6, c = t & 63;
    const float* W = (layer < 8) ? (Ws + layer * 4096) : Wn;
    int ct = c >> 4, lr = c & 15, ks = k >> 5, lg = (k >> 3) & 3, j = k & 7;
    Wt[layer * 4096 + (((ct * 2 + ks) * 4 + lg) * 16 + lr) * 8 + j] = f2bf(W[k * 64 + c]);
}

// ---------------- layer 0 input GEMM via MFMA: h'0 = (x @ W0) * dinv, bf16 out ----------------

__global__ __launch_bounds__(256) void gemm0_kernel(const float* __restrict__ x,
                                                    const float* __restrict__ W0,
                                                    const float* __restrict__ dinv,
                                                    u16* __restrict__ out) {
    __shared__ float Wlds[C_IN * C_H];   // 32 KB fp32
    for (int t = threadIdx.x; t < (C_IN * C_H) / 4; t += 256)
        *(float4*)&Wlds[t * 4] = *(const float4*)&W0[t * 4];
    __syncthreads();

    int wid = threadIdx.x >> 6, lane = threadIdx.x & 63;
    int lr = lane & 15, lg = lane >> 4;

    bf16x8 bfr[4][4];   // [col-tile][k-step]
#pragma unroll
    for (int ct = 0; ct < 4; ct++)
#pragma unroll
        for (int kk = 0; kk < 4; kk++)
#pragma unroll
            for (int j = 0; j < 8; j++)
                bfr[ct][kk][j] = (__bf16)Wlds[(kk * 32 + lg * 8 + j) * C_H + ct * 16 + lr];

    for (int t = blockIdx.x * 4 + wid; t < N_NODES / 16; t += gridDim.x * 4) {
        int row0 = t * 16;
        bf16x8 af[4];
#pragma unroll
        for (int kk = 0; kk < 4; kk++) {
            const float* xp = x + (size_t)(row0 + lr) * C_IN + kk * 32 + lg * 8;
            float4 p0 = *(const float4*)xp;
            float4 p1 = *(const float4*)(xp + 4);
            af[kk][0] = (__bf16)p0.x; af[kk][1] = (__bf16)p0.y;
            af[kk][2] = (__bf16)p0.z; af[kk][3] = (__bf16)p0.w;
            af[kk][4] = (__bf16)p1.x; af[kk][5] = (__bf16)p1.y;
            af[kk][6] = (__bf16)p1.z; af[kk][7] = (__bf16)p1.w;
        }
        f32x4 acc[4];
#pragma unroll
        for (int ct = 0; ct < 4; ct++) acc[ct] = (f32x4){0.f, 0.f, 0.f, 0.f};
#pragma unroll
        for (int ct = 0; ct < 4; ct++)
#pragma unroll
            for (int kk = 0; kk < 4; kk++)
                acc[ct] = __builtin_amdgcn_mfma_f32_16x16x32_bf16(af[kk], bfr[ct][kk], acc[ct], 0, 0, 0);
#pragma unroll
        for (int reg = 0; reg < 4; reg++) {
            int rr = row0 + lg * 4 + reg;
            float dv = dinv[rr];
#pragma unroll
            for (int ct = 0; ct < 4; ct++)
                out[(size_t)rr * C_H + ct * 16 + lr] = f2bf(acc[ct][reg] * dv);
        }
    }
}

// ---------------- fused layer: depth-2 pipelined gather + MFMA GEMV (frag-packed W) --------

#define CLOAD(dst, n, d, b_)                                                      \
    {                                                                             \
        int e_ = (b_) + 8 * (d) + g;                                              \
        int s_ = csr16[sq##n + ((e_ < dq##n) ? e_ : 0)];                          \
        dst = (e_ < dq##n) ? s_ : N_NODES;                                        \
    }

#define ROWAS(v_, s_) v_ = *(const uint4*)(hw + (size_t)(s_) * C_HU + r * 4);

#define RED(Aq)                                                                   \
    _Pragma("unroll")                                                             \
    for (int c = 0; c < 8; c++) {                                                 \
        Aq[c] += __shfl_xor(Aq[c], 8);                                            \
        Aq[c] += __shfl_xor(Aq[c], 16);                                           \
        Aq[c] += __shfl_xor(Aq[c], 32);                                           \
    }

#define EPILOG(q, iq, Aq)                                                         \
    {                                                                             \
        float di = dinv[iq];                                                      \
        uint4 sv = *(const uint4*)(hw + (size_t)(iq) * C_HU + r * 4);             \
        if (g == 0) {                                                             \
            float h0 = fmaxf(di * (Aq[0] + bflo(sv.x)) + b8[0], 0.f);             \
            float h1 = fmaxf(di * (Aq[1] + bfhi(sv.x)) + b8[1], 0.f);             \
            float h2 = fmaxf(di * (Aq[2] + bflo(sv.y)) + b8[2], 0.f);             \
            float h3 = fmaxf(di * (Aq[3] + bfhi(sv.y)) + b8[3], 0.f);             \
            float h4 = fmaxf(di * (Aq[4] + bflo(sv.z)) + b8[4], 0.f);             \
            float h5 = fmaxf(di * (Aq[5] + bfhi(sv.z)) + b8[5], 0.f);             \
            float h6 = fmaxf(di * (Aq[6] + bflo(sv.w)) + b8[6], 0.f);             \
            float h7 = fmaxf(di * (Aq[7] + bfhi(sv.w)) + b8[7], 0.f);             \
            uint4 pk;                                                             \
            pk.x = (u32)f2bf(h0) | ((u32)f2bf(h1) << 16);                         \
            pk.y = (u32)f2bf(h2) | ((u32)f2bf(h3) << 16);                         \
            pk.z = (u32)f2bf(h4) | ((u32)f2bf(h5) << 16);                         \
            pk.w = (u32)f2bf(h6) | ((u32)f2bf(h7) << 16);                         \
            int n_ = wave * 4 + q;                                                \
            int rs_ = r ^ (n_ & 7);     /* chunk swizzle: 16B chunks */           \
            *(uint4*)&hbuf32[n_ * 32 + rs_ * 4] = pk;                             \
        }                                                                         \
    }

__global__ __launch_bounds__(256) void layer_kernel(const u32* __restrict__ hw,
                                                    const int* __restrict__ rowStart,
                                                    const int* __restrict__ cnt,
                                                    const u16* __restrict__ csr16,
                                                    const float* __restrict__ dinv,
                                                    const float* __restrict__ bias,
                                                    const u16* __restrict__ wtL,
                                                    int scaled,
                                                    u16* __restrict__ out) {
    __shared__ u32 hbuf32[NPB * C_HU];   // 16 nodes x 64ch bf16 = 2 KB

    int wave = threadIdx.x >> 6, lane = threadIdx.x & 63;
    int g = lane >> 3;          // edge sub-group 0..7
    int r = lane & 7;           // channel chunk: channels 8r..8r+7
    int jblock = blockIdx.x * NPB;
    int jbase = jblock + wave * 4;

    int i0 = jbase + 0, i1 = jbase + 1, i2 = jbase + 2, i3 = jbase + 3;
    int sq0 = rowStart[i0], sq1 = rowStart[i1], sq2 = rowStart[i2], sq3 = rowStart[i3];
    int dq0 = cnt[i0], dq1 = cnt[i1], dq2 = cnt[i2], dq3 = cnt[i3];
    int dmax = max(max(dq0, dq1), max(dq2, dq3));

    float A0[8] = {0.f,0.f,0.f,0.f,0.f,0.f,0.f,0.f};
    float A1[8] = {0.f,0.f,0.f,0.f,0.f,0.f,0.f,0.f};
    float A2[8] = {0.f,0.f,0.f,0.f,0.f,0.f,0.f,0.f};
    float A3[8] = {0.f,0.f,0.f,0.f,0.f,0.f,0.f,0.f};

    // ---- pipeline prologue: csr batch 0, rows batch 0, csr batch 1 ----
    int s00, s01, s10, s11, s20, s21, s30, s31;
    CLOAD(s00, 0, 0, 0) CLOAD(s01, 0, 1, 0)
    CLOAD(s10, 1, 0, 0) CLOAD(s11, 1, 1, 0)
    CLOAD(s20, 2, 0, 0) CLOAD(s21, 2, 1, 0)
    CLOAD(s30, 3, 0, 0) CLOAD(s31, 3, 1, 0)

    uint4 v00, v01, v10, v11, v20, v21, v30, v31;
    ROWAS(v00, s00) ROWAS(v01, s01)
    ROWAS(v10, s10) ROWAS(v11, s11)
    ROWAS(v20, s20) ROWAS(v21, s21)
    ROWAS(v30, s30) ROWAS(v31, s31)

    int t00, t01, t10, t11, t20, t21, t30, t31;
    CLOAD(t00, 0, 0, 16) CLOAD(t01, 0, 1, 16)
    CLOAD(t10, 1, 0, 16) CLOAD(t11, 1, 1, 16)
    CLOAD(t20, 2, 0, 16) CLOAD(t21, 2, 1, 16)
    CLOAD(t30, 3, 0, 16) CLOAD(t31, 3, 1, 16)

    for (int base = 0; base < dmax; base += 16) {
        // issue next batch's rows (from t) — consumed NEXT iteration
        uint4 n00, n01, n10, n11, n20, n21, n30, n31;
        ROWAS(n00, t00) ROWAS(n01, t01)
        ROWAS(n10, t10) ROWAS(n11, t11)
        ROWAS(n20, t20) ROWAS(n21, t21)
        ROWAS(n30, t30) ROWAS(n31, t31)
        // prefetch csr for batch i+2
        int nb = base + 32;
        int u00, u01, u10, u11, u20, u21, u30, u31;
        CLOAD(u00, 0, 0, nb) CLOAD(u01, 0, 1, nb)
        CLOAD(u10, 1, 0, nb) CLOAD(u11, 1, 1, nb)
        CLOAD(u20, 2, 0, nb) CLOAD(u21, 2, 1, nb)
        CLOAD(u30, 3, 0, nb) CLOAD(u31, 3, 1, nb)
        // consume current batch (loaded one iteration ago — latency hidden)
        add8(A0, v00); add8(A0, v01);
        add8(A1, v10); add8(A1, v11);
        add8(A2, v20); add8(A2, v21);
        add8(A3, v30); add8(A3, v31);
        // rotate
        v00 = n00; v01 = n01; v10 = n10; v11 = n11;
        v20 = n20; v21 = n21; v30 = n30; v31 = n31;
        t00 = u00; t01 = u01; t10 = u10; t11 = u11;
        t20 = u20; t21 = u21; t30 = u30; t31 = u31;
    }

    RED(A0) RED(A1) RED(A2) RED(A3)

    float b8[8];
    *(float4*)&b8[0] = *(const float4*)(bias + r * 8);
    *(float4*)&b8[4] = *(const float4*)(bias + r * 8 + 4);

    EPILOG(0, i0, A0)
    EPILOG(1, i1, A1)
    EPILOG(2, i2, A2)
    EPILOG(3, i3, A3)

    __syncthreads();   // hbuf visibility

    // ---- GEMV via MFMA: wave ct computes cols ct*16..+15 for all 16 nodes ----
    {
        int ct = wave;
        int lr = lane & 15, lg = lane >> 4;
        bf16x8 bw0 = *(const bf16x8*)&wtL[(((ct * 2 + 0) * 4 + lg) * 16 + lr) * 8];
        bf16x8 bw1 = *(const bf16x8*)&wtL[(((ct * 2 + 1) * 4 + lg) * 16 + lr) * 8];
        const u16* hb = (const u16*)hbuf32;
        bf16x8 ah[2];
#pragma unroll
        for (int ks = 0; ks < 2; ks++) {
            int c = lg + 4 * ks;
            int cs = c ^ (lr & 7);
            ah[ks] = *(const bf16x8*)&hb[lr * C_H + cs * 8];
        }
        f32x4 accv = (f32x4){0.f, 0.f, 0.f, 0.f};
        accv = __builtin_amdgcn_mfma_f32_16x16x32_bf16(ah[0], bw0, accv, 0, 0, 0);
        accv = __builtin_amdgcn_mfma_f32_16x16x32_bf16(ah[1], bw1, accv, 0, 0, 0);
        float4 dv4 = *(const float4*)(dinv + jblock + lg * 4);
        float dvs[4] = {dv4.x, dv4.y, dv4.z, dv4.w};
#pragma unroll
        for (int reg = 0; reg < 4; reg++) {
            int nn = jblock + lg * 4 + reg;
            float sc_ = scaled ? dvs[reg] : 1.0f;
            out[(size_t)nn * C_H + ct * 16 + lr] = f2bf(accv[reg] * sc_);
        }
    }
}

// ---------------- pooling head ----------------

__global__ __launch_bounds__(256) void pool_kernel(const u16* __restrict__ hn,
                                                   float* __restrict__ poolbuf) {
    int g = blockIdx.x >> 4;
    int s = blockIdx.x & 15;
    int lane = threadIdx.x & 63;
    int rg = threadIdx.x >> 6;
    int stream = s * 4 + rg;
    float acc = 0.f;
    for (int r = stream; r < N_PER_G; r += 64)
        acc += bflo((u32)hn[(size_t)(g * N_PER_G + r) * C_H + lane]);
    __shared__ float red[4][C_H];
    red[rg][lane] = acc;
    __syncthreads();
    if (rg == 0) {
        float t = red[0][lane] + red[1][lane] + red[2][lane] + red[3][lane];
        atomicAdd(&poolbuf[g * C_H + lane], t);
    }
}

__global__ void poolwp_kernel(const float* __restrict__ poolbuf,
                              const float* __restrict__ Wp,
                              float* __restrict__ poolwp) {
    int g = blockIdx.x, c = threadIdx.x;
    float o = 0.f;
#pragma unroll 8
    for (int k = 0; k < C_H; k++) o += poolbuf[g * C_H + k] * Wp[k * C_H + c];
    poolwp[g * C_H + c] = o;
}

__global__ __launch_bounds__(256) void final_kernel(const u16* __restrict__ hn,
                                                    const float* __restrict__ poolwp,
                                                    const float* __restrict__ Wa,
                                                    float* __restrict__ out, int n) {
    int wave = threadIdx.x >> 6, lane = threadIdx.x & 63;
    int i = blockIdx.x * 4 + wave;
    if (i >= n) return;
    int g = i / N_PER_G;
    float v = fmaxf(bflo((u32)hn[(size_t)i * C_H + lane]), 0.f) * Wa[lane]
            + fmaxf(poolwp[g * C_H + lane], 0.f) * Wa[C_H + lane];
#pragma unroll
    for (int off = 32; off; off >>= 1) v += __shfl_down(v, off);
    if (lane == 0) out[i] = tanhf(v);
}

// ---------------- launch ----------------

extern "C" void kernel_launch(void* const* d_in, const int* in_sizes, int n_in,
                              void* d_out, int out_size, void* d_ws, size_t ws_size,
                              hipStream_t stream) {
    const float* x   = (const float*)d_in[0];
    const int*   ei  = (const int*)d_in[1];
    const float* W0  = (const float*)d_in[2];
    const float* b0  = (const float*)d_in[3];
    const float* Ws  = (const float*)d_in[4];
    const float* bs  = (const float*)d_in[5];
    const float* Wn  = (const float*)d_in[6];
    const float* Wp  = (const float*)d_in[7];
    const float* Wa  = (const float*)d_in[8];
    float* out = (float*)d_out;

    const int* e_src = ei;
    const int* e_dst = ei + N_EDGES;

    size_t off = 0;
    auto alloc = [&](size_t bytes) { size_t o = off; off = (off + bytes + 255) & ~(size_t)255; return o; };
    char* ws = (char*)d_ws;
    int*   cnt      = (int*)  (ws + alloc(N_NODES * 4));
    int*   rowStart = (int*)  (ws + alloc(N_NODES * 4));
    int*   cursor   = (int*)  (ws + alloc(N_NODES * 4));
    float* dinv     = (float*)(ws + alloc(N_NODES * 4));
    int*   bsum     = (int*)  (ws + alloc(NSB * 4));
    u16*   csr16    = (u16*)  (ws + alloc((size_t)(N_EDGES + 64) * 2));   // +pad
    u16*   Wt       = (u16*)  (ws + alloc((size_t)9 * 4096 * 2));         // frag-packed weights
    u16*   bufA     = (u16*)  (ws + alloc((size_t)(N_NODES + 1) * C_H * 2));  // +1 zero sentinel row
    u16*   bufB     = (u16*)  (ws + alloc((size_t)(N_NODES + 1) * C_H * 2));
    float* poolbuf  = (float*)(ws + alloc(N_GRAPH * C_H * 4));
    float* poolwp   = (float*)(ws + alloc(N_GRAPH * C_H * 4));

    hipMemsetAsync(cnt, 0, N_NODES * 4, stream);
    hipMemsetAsync(poolbuf, 0, N_GRAPH * C_H * 4, stream);
    hipMemsetAsync(bufA + (size_t)N_NODES * C_H, 0, C_H * 2, stream);   // zero sentinel rows
    hipMemsetAsync(bufB + (size_t)N_NODES * C_H, 0, C_H * 2, stream);

    count_kernel<<<1024, 256, 0, stream>>>(e_dst, cnt);
    bsum_kernel<<<NSB, 256, 0, stream>>>(cnt, bsum);
    scan2_kernel<<<NSB, 256, 0, stream>>>(cnt, bsum, rowStart, cursor, dinv);
    scatter_kernel<<<1024, 256, 0, stream>>>(e_src, e_dst, cursor, csr16);
    wtrans_kernel<<<144, 256, 0, stream>>>(Ws, Wn, Wt);

    gemm0_kernel<<<391, 256, 0, stream>>>(x, W0, dinv, bufA);   // h'0 = (x@W0)*dinv

    const int LB = N_NODES / NPB;   // 3125
    for (int k = 0; k < N_LAYER; k++) {
        const u16* hin  = (k & 1) ? bufB : bufA;
        u16*       hout = (k & 1) ? bufA : bufB;
        const float* bias = (k == 0) ? b0 : (bs + (k - 1) * C_H);
        const u16* wtL = Wt + k * 4096;
        int scaled = (k < N_LAYER - 1) ? 1 : 0;
        layer_kernel<<<LB, 256, 0, stream>>>((const u32*)hin, rowStart, cnt, csr16,
                                             dinv, bias, wtL, scaled, hout);
    }
    const u16* hn = bufB;   // layer 8 output

    pool_kernel<<<N_GRAPH * 16, 256, 0, stream>>>(hn, poolbuf);
    poolwp_kernel<<<N_GRAPH, C_H, 0, stream>>>(poolbuf, Wp, poolwp);
    final_kernel<<<N_NODES / 4, 256, 0, stream>>>(hn, poolwp, Wa, out, N_NODES);
}